// Round 5
// baseline (371.667 us; speedup 1.0000x reference)
//
#include <hip/hip_runtime.h>
#include <hip/hip_bf16.h>

#define NB 32
#define CH 64
#define TF 300
#define VJ 25
#define NSUB 3
#define ICB 16
#define KW 9
#define EPSB 1e-5f

#define TVsz (TF*VJ)          // 7500
#define CTVsz (CH*TF*VJ)      // 480000
#define TOTAL (NB*CTVsz)      // 15360000
#define PCCOUNT (NB*TF*VJ)    // 240000

#define NCHUNK 16             // n per chunk for g
#define NTILES 59             // ceil(7500/128) for k_g
#define ATC 32                // t per attention chunk
#define ATCN 10               // ceil(300/32)

typedef __attribute__((ext_vector_type(8))) short s16x8;
typedef __attribute__((ext_vector_type(4))) float f32x4;

__device__ __forceinline__ unsigned short f2bf(float v) {
    __hip_bfloat16 h = __float2bfloat16(v);
    return *(unsigned short*)&h;
}
__device__ __forceinline__ float bf2f(unsigned int u) {
    return __uint_as_float(u << 16);
}

// ---------------- merged weight prep ----------------
// awT: Wt [o][c][k] -> [k][o][c] bf16 ; wdcat: Wd flat bf16 ;
// wcat: [i][32 rows a|b][64c] bf16 ; biascat[96] f32
__global__ void k_prep(const float* __restrict__ Wt, const float* __restrict__ Wd,
                       const float* __restrict__ Wa, const float* __restrict__ ba,
                       const float* __restrict__ Wb, const float* __restrict__ bb,
                       unsigned short* __restrict__ awT, unsigned short* __restrict__ wdcat,
                       unsigned short* __restrict__ wcat, float* __restrict__ biascat) {
    int e = blockIdx.x * 256 + threadIdx.x;
    if (e < CH*CH*KW) {
        int o = e / (CH*KW), c = (e / KW) % CH, k = e % KW;
        awT[(k*CH + o)*CH + c] = f2bf(Wt[e]);
        return;
    }
    int e2 = e - CH*CH*KW;
    if (e2 < NSUB*CH*CH) { wdcat[e2] = f2bf(Wd[e2]); return; }
    int e3 = e2 - NSUB*CH*CH;
    if (e3 < 6144) {
        int i = e3 / 2048, rm = (e3 >> 6) & 31, c = e3 & 63;
        wcat[e3] = f2bf((rm < 16) ? Wa[(i*ICB + rm)*CH + c] : Wb[(i*ICB + rm - 16)*CH + c]);
        return;
    }
    if (e3 < 6240) {
        int j = e3 - 6144;
        int i = j >> 5, r = j & 31;
        biascat[j] = (r < 16) ? ba[i*ICB + r] : bb[i*ICB + r - 16];
    }
}

// ---------------- x transpose (all n): [n][c][tv] f32 -> [n][tv][c] bf16 ----
__global__ __launch_bounds__(256) void k_xt(const float* __restrict__ x,
                                            unsigned short* __restrict__ xbt) {
    __shared__ unsigned short ls[64*66];
    int b = blockIdx.x;
    int n = b / 118, tile = b % 118;
    int tv0 = tile * 64;
    int tid = threadIdx.x;
    const float* xg = x + (long)n * CTVsz;
    for (int e = tid; e < 1024; e += 256) {
        int c = e >> 4, t4 = (e & 15) * 4;
        int tv = tv0 + t4;
        if (tv < TVsz) {   // TVsz % 4 == 0 so a valid start implies 4 valid
            float4 v = *(const float4*)(xg + (long)c*TVsz + tv);
            ls[(t4+0)*66 + c] = f2bf(v.x);
            ls[(t4+1)*66 + c] = f2bf(v.y);
            ls[(t4+2)*66 + c] = f2bf(v.z);
            ls[(t4+3)*66 + c] = f2bf(v.w);
        }
    }
    __syncthreads();
    for (int e = tid; e < 1024; e += 256) {
        int tvl = e >> 4, c4 = (e & 15) * 4;
        int tv = tv0 + tvl;
        if (tv < TVsz) {
            unsigned int lo = *(const unsigned int*)&ls[tvl*66 + c4];
            unsigned int hi = *(const unsigned int*)&ls[tvl*66 + c4 + 2];
            *(uint2*)&xbt[((long)n*TVsz + tv)*CH + c4] = make_uint2(lo, hi);
        }
    }
}

// ---------------- attention: emb MFMA -> LDS -> Gram MFMA -> atomics --------
__global__ __launch_bounds__(256) void k_attn(
    const unsigned short* __restrict__ xbt, const unsigned short* __restrict__ wcat,
    const float* __restrict__ biascat, float* __restrict__ Mbuf)
{
    __shared__ __align__(16) char emb[32*32*ATC*2];
    __shared__ float gram[625];
    int b = blockIdx.x;
    int i   = b / (NB*ATCN);
    int rem = b % (NB*ATCN);
    int n = rem / ATCN, tc = rem % ATCN;
    int t0 = tc * ATC;
    int tid = threadIdx.x;
    int wv = tid >> 6, l = tid & 63, l15 = l & 15, lhi = l >> 4;

    for (int e = tid; e < 625; e += 256) gram[e] = 0.f;

    s16x8 wf[2][2];
    #pragma unroll
    for (int mf = 0; mf < 2; ++mf)
        #pragma unroll
        for (int kc = 0; kc < 2; ++kc)
            wf[mf][kc] = *(const s16x8*)(wcat + ((i*32 + mf*16 + l15)*64 + kc*32 + lhi*8));
    float bs[2][4];
    #pragma unroll
    for (int mf = 0; mf < 2; ++mf)
        #pragma unroll
        for (int r = 0; r < 4; ++r)
            bs[mf][r] = biascat[i*32 + mf*16 + lhi*4 + r];

    const unsigned short* xb = xbt + (long)n * TVsz * CH;
    for (int v = wv; v < 25; v += 4) {
        f32x4 ae[2][2];
        #pragma unroll
        for (int mf = 0; mf < 2; ++mf)
            #pragma unroll
            for (int nf = 0; nf < 2; ++nf)
                ae[mf][nf] = (f32x4){0.f,0.f,0.f,0.f};
        #pragma unroll
        for (int nf = 0; nf < 2; ++nf) {
            int t = t0 + nf*16 + l15;
            int tcl = t < TF ? t : TF-1;
            const unsigned short* bp = xb + ((long)tcl*VJ + v)*CH;
            s16x8 b0 = *(const s16x8*)(bp + lhi*8);
            s16x8 b1 = *(const s16x8*)(bp + 32 + lhi*8);
            #pragma unroll
            for (int mf = 0; mf < 2; ++mf) {
                ae[mf][nf] = __builtin_amdgcn_mfma_f32_16x16x32_bf16(wf[mf][0], b0, ae[mf][nf], 0,0,0);
                ae[mf][nf] = __builtin_amdgcn_mfma_f32_16x16x32_bf16(wf[mf][1], b1, ae[mf][nf], 0,0,0);
            }
        }
        #pragma unroll
        for (int mf = 0; mf < 2; ++mf)
            #pragma unroll
            for (int nf = 0; nf < 2; ++nf)
                #pragma unroll
                for (int r = 0; r < 4; ++r) {
                    int t  = t0 + nf*16 + l15;
                    int tl = nf*16 + l15;
                    int m  = mf*16 + lhi*4 + r;
                    float val = (t < TF) ? (ae[mf][nf][r] + bs[mf][r]) : 0.f;
                    int byte = (((v*32 + m)*ATC + tl)*2) ^ ((v&7)<<4);
                    *(unsigned short*)(emb + byte) = f2bf(val);
                }
    }
    __syncthreads();

    f32x4 ag[2][2];
    #pragma unroll
    for (int mu = 0; mu < 2; ++mu)
        #pragma unroll
        for (int nw = 0; nw < 2; ++nw)
            ag[mu][nw] = (f32x4){0.f,0.f,0.f,0.f};
    #pragma unroll
    for (int oo = 0; oo < 4; ++oo) {
        int o = wv*4 + oo;
        s16x8 fa[2], fb[2];
        #pragma unroll
        for (int mu = 0; mu < 2; ++mu) {
            int u = mu*16 + l15; if (u > 24) u = 24;
            fa[mu] = *(const s16x8*)(emb + ((((u*32 + o)*ATC + lhi*8)*2) ^ ((u&7)<<4)));
        }
        #pragma unroll
        for (int nw = 0; nw < 2; ++nw) {
            int w = nw*16 + l15; if (w > 24) w = 24;
            fb[nw] = *(const s16x8*)(emb + ((((w*32 + 16 + o)*ATC + lhi*8)*2) ^ ((w&7)<<4)));
        }
        #pragma unroll
        for (int mu = 0; mu < 2; ++mu)
            #pragma unroll
            for (int nw = 0; nw < 2; ++nw)
                ag[mu][nw] = __builtin_amdgcn_mfma_f32_16x16x32_bf16(fa[mu], fb[nw], ag[mu][nw], 0,0,0);
    }
    #pragma unroll
    for (int mu = 0; mu < 2; ++mu)
        #pragma unroll
        for (int nw = 0; nw < 2; ++nw)
            #pragma unroll
            for (int r = 0; r < 4; ++r) {
                int u = mu*16 + lhi*4 + r;
                int w = nw*16 + l15;
                if (u < 25 && w < 25)
                    atomicAdd(&gram[u*25 + w], ag[mu][nw][r]);
            }
    __syncthreads();
    for (int e = tid; e < 625; e += 256)
        atomicAdd(&Mbuf[(i*NB + n)*625 + e], gram[e]);
}

// ---------------- column softmax + A+PA ----------------
__global__ void k_softmax(const float* __restrict__ A, const float* __restrict__ PA,
                          float* __restrict__ Mbuf) {
    int b = blockIdx.x;
    int i = b / NB;
    int w = threadIdx.x;
    if (w >= 25) return;
    float* M = Mbuf + b*625;
    const float scale = 1.0f / (float)(ICB * TF);
    float col[25];
    float mx = -1e30f;
    #pragma unroll
    for (int u = 0; u < 25; ++u) { col[u] = M[u*25 + w] * scale; mx = fmaxf(mx, col[u]); }
    float s = 0.f;
    #pragma unroll
    for (int u = 0; u < 25; ++u) { col[u] = __expf(col[u] - mx); s += col[u]; }
    float inv = 1.0f / s;
    #pragma unroll
    for (int u = 0; u < 25; ++u)
        M[u*25 + w] = col[u]*inv + A[i*625 + u*25 + w] + PA[i*625 + u*25 + w];
}

// ---------------- GEMM1: g = Wdcat[192,64] x[64,7500] per n (chunk) --------
__global__ __launch_bounds__(256) void k_g(const unsigned short* __restrict__ xbt,
                                           const unsigned short* __restrict__ wdcat,
                                           unsigned short* __restrict__ g) {
    int b = blockIdx.x;
    int nc = b / NTILES, tile = b % NTILES;
    int tv0 = tile * 128;
    int tid = threadIdx.x;
    int w = tid >> 6, wm = w >> 1, wn = w & 1;
    int l = tid & 63, l15 = l & 15, lhi = l >> 4;

    s16x8 af[6][2];
    #pragma unroll
    for (int mf = 0; mf < 6; ++mf)
        #pragma unroll
        for (int kc = 0; kc < 2; ++kc)
            af[mf][kc] = *(const s16x8*)(wdcat + ((wm*96 + mf*16 + l15)*64 + kc*32 + lhi*8));

    f32x4 acc[6][4];
    #pragma unroll
    for (int mf = 0; mf < 6; ++mf)
        #pragma unroll
        for (int nf = 0; nf < 4; ++nf)
            acc[mf][nf] = (f32x4){0.f,0.f,0.f,0.f};

    const unsigned short* xb = xbt + (long)nc * TVsz * CH;
    #pragma unroll
    for (int nf = 0; nf < 4; ++nf) {
        int tv = tv0 + wn*64 + nf*16 + l15;
        int tvc = tv < TVsz ? tv : TVsz-1;
        s16x8 b0 = *(const s16x8*)(xb + (long)tvc*CH + lhi*8);
        s16x8 b1 = *(const s16x8*)(xb + (long)tvc*CH + 32 + lhi*8);
        #pragma unroll
        for (int mf = 0; mf < 6; ++mf) {
            acc[mf][nf] = __builtin_amdgcn_mfma_f32_16x16x32_bf16(af[mf][0], b0, acc[mf][nf], 0,0,0);
            acc[mf][nf] = __builtin_amdgcn_mfma_f32_16x16x32_bf16(af[mf][1], b1, acc[mf][nf], 0,0,0);
        }
    }

    #pragma unroll
    for (int nf = 0; nf < 4; ++nf) {
        int tv = tv0 + wn*64 + nf*16 + l15;
        if (tv < TVsz) {
            int t = tv / 25, u = tv % 25;
            #pragma unroll
            for (int mf = 0; mf < 6; ++mf) {
                #pragma unroll
                for (int r = 0; r < 4; ++r) {
                    int m = wm*96 + mf*16 + lhi*4 + r;
                    long base = (((long)nc*192 + m)*TF + t)*32;
                    g[base + u] = f2bf(acc[mf][nf][r]);
                    if (u == 24) {
                        #pragma unroll
                        for (int p = 25; p < 32; ++p) g[base + p] = 0;
                    }
                }
            }
        }
    }
}

// -------- GEMM2 + fused BN1 partial stats: y (bf16) = sum_i g*attn + bd -----
__global__ __launch_bounds__(256) void k_y2(const unsigned short* __restrict__ g,
                                            const float* __restrict__ Mbuf,
                                            const float* __restrict__ bd,
                                            unsigned short* __restrict__ ybuf,
                                            float* __restrict__ s1, float* __restrict__ s2,
                                            int n0) {
    __shared__ unsigned short attnT[32][104];
    __shared__ float sp[4], sq[4];
    int b = blockIdx.x;
    int nc = b / 320;
    int rem = b % 320;
    int o = rem / 5, tb = rem % 5;
    int n = n0 + nc;
    int tid = threadIdx.x;

    for (int e = tid; e < 32*104; e += 256) ((unsigned short*)attnT)[e] = 0;
    __syncthreads();
    for (int e = tid; e < 3*625; e += 256) {
        int i = e / 625, uw = e % 625;
        int u = uw / 25, v = uw % 25;
        attnT[v][i*32 + u] = f2bf(Mbuf[(i*NB + n)*625 + uw]);
    }
    __syncthreads();

    int w = tid >> 6, l = tid & 63, l15 = l & 15, lhi = l >> 4;
    int t0 = tb*64 + w*16;

    f32x4 acc[2];
    acc[0] = (f32x4){0.f,0.f,0.f,0.f};
    acc[1] = (f32x4){0.f,0.f,0.f,0.f};

    #pragma unroll
    for (int kc = 0; kc < 3; ++kc) {
        int t = t0 + l15; if (t > 299) t = 299;
        s16x8 a = *(const s16x8*)(g + ((((long)nc*192 + kc*64 + o)*TF + t)*32 + lhi*8));
        #pragma unroll
        for (int nf = 0; nf < 2; ++nf) {
            s16x8 bfr = *(const s16x8*)(&attnT[nf*16 + l15][kc*32 + lhi*8]);
            acc[nf] = __builtin_amdgcn_mfma_f32_16x16x32_bf16(a, bfr, acc[nf], 0,0,0);
        }
    }

    float bds = bd[o] + bd[CH + o] + bd[2*CH + o];
    float p = 0.f, q = 0.f;
    #pragma unroll
    for (int nf = 0; nf < 2; ++nf) {
        #pragma unroll
        for (int r = 0; r < 4; ++r) {
            int t = t0 + lhi*4 + r;
            int v = nf*16 + l15;
            if (t < TF && v < VJ) {
                float val = acc[nf][r] + bds;
                ybuf[((long)n*CH + o)*TVsz + t*25 + v] = f2bf(val);
                p += val; q += val*val;
            }
        }
    }
    #pragma unroll
    for (int m = 1; m < 64; m <<= 1) {
        p += __shfl_xor(p, m, 64);
        q += __shfl_xor(q, m, 64);
    }
    if (l == 0) { sp[w] = p; sq[w] = q; }
    __syncthreads();
    if (tid == 0) {
        atomicAdd(&s1[o], sp[0]+sp[1]+sp[2]+sp[3]);
        atomicAdd(&s2[o], sq[0]+sq[1]+sq[2]+sq[3]);
    }
}

// ---------------- y = relu(bn1(y)+x) -> bf16 transposed [n][tv][c] ----------
__global__ __launch_bounds__(256) void k_bn1t(
    const float* __restrict__ x, const float* __restrict__ g1, const float* __restrict__ b1,
    const float* __restrict__ s1, const float* __restrict__ s2,
    const unsigned short* __restrict__ yb, unsigned short* __restrict__ ybt)
{
    __shared__ unsigned short ls[64*66];
    int b = blockIdx.x;
    int n = b / 118, tile = b % 118;
    int tv0 = tile * 64;
    const float invN = 1.0f / (float)PCCOUNT;
    int tid = threadIdx.x;

    for (int e = tid; e < 1024; e += 256) {
        int c = e >> 4, t4 = (e & 15) * 4;
        int tv = tv0 + t4;
        if (tv < TVsz) {   // TVsz % 4 == 0
            long gbase = (long)n*CTVsz + (long)c*TVsz;
            float m  = s1[c] * invN;
            float vr = s2[c] * invN - m*m;
            float sc = rsqrtf(vr + EPSB) * g1[c];
            float bc = b1[c];
            uint2 yv = *(const uint2*)(yb + gbase + tv);
            float4 xv = *(const float4*)(x + gbase + tv);
            ls[(t4+0)*66 + c] = f2bf(fmaxf((bf2f(yv.x & 0xffffu) - m)*sc + bc + xv.x, 0.f));
            ls[(t4+1)*66 + c] = f2bf(fmaxf((bf2f(yv.x >> 16)     - m)*sc + bc + xv.y, 0.f));
            ls[(t4+2)*66 + c] = f2bf(fmaxf((bf2f(yv.y & 0xffffu) - m)*sc + bc + xv.z, 0.f));
            ls[(t4+3)*66 + c] = f2bf(fmaxf((bf2f(yv.y >> 16)     - m)*sc + bc + xv.w, 0.f));
        }
    }
    __syncthreads();
    for (int e = tid; e < 1024; e += 256) {
        int tvl = e >> 4, c4 = (e & 15) * 4;
        int tv = tv0 + tvl;
        if (tv < TVsz) {
            unsigned int lo = *(const unsigned int*)&ls[tvl*66 + c4];
            unsigned int hi = *(const unsigned int*)&ls[tvl*66 + c4 + 2];
            *(uint2*)&ybt[((long)n*TVsz + tv)*CH + c4] = make_uint2(lo, hi);
        }
    }
}

// ------- temporal conv via MFMA, no LDS staging, fused BN2 partial stats ----
#define NTILE 256

__global__ __launch_bounds__(256) void k_tconv(
    const unsigned short* __restrict__ ybt, const unsigned short* __restrict__ awT,
    const float* __restrict__ bt, unsigned short* __restrict__ ycb,
    float* __restrict__ s1, float* __restrict__ s2)
{
    __shared__ float ss[64], sq[64];
    int b = blockIdx.x;
    int n = b / 30, tile = b % 30;
    int tv0 = tile * NTILE;
    int tid = threadIdx.x;
    int wv = tid >> 6, l = tid & 63, l15 = l & 15, lhi = l >> 4;
    if (tid < 64) { ss[tid] = 0.f; sq[tid] = 0.f; }

    const unsigned short* src = ybt + (long)n * TVsz * CH;
    int rbase = tv0 - 100 + wv*64 + l15;

    f32x4 acc[4][4];
    #pragma unroll
    for (int mf = 0; mf < 4; ++mf)
        #pragma unroll
        for (int nf = 0; nf < 4; ++nf)
            acc[mf][nf] = (f32x4){0.f, 0.f, 0.f, 0.f};

    const short* aw = (const short*)awT;
    const s16x8 bz = (s16x8){0,0,0,0,0,0,0,0};
    for (int tap = 0; tap < KW; ++tap) {
        #pragma unroll
        for (int kc = 0; kc < 2; ++kc) {
            s16x8 af[4], bfr[4];
            #pragma unroll
            for (int mf = 0; mf < 4; ++mf)
                af[mf] = *(const s16x8*)(aw + ((tap*CH + mf*16 + l15)*CH + kc*32 + lhi*8));
            #pragma unroll
            for (int nf = 0; nf < 4; ++nf) {
                int row = rbase + nf*16 + tap*25;
                bfr[nf] = (row >= 0 && row < TVsz)
                          ? *(const s16x8*)(src + (long)row*CH + kc*32 + lhi*8) : bz;
            }
            #pragma unroll
            for (int mf = 0; mf < 4; ++mf)
                #pragma unroll
                for (int nf = 0; nf < 4; ++nf)
                    acc[mf][nf] = __builtin_amdgcn_mfma_f32_16x16x32_bf16(
                        af[mf], bfr[nf], acc[mf][nf], 0, 0, 0);
        }
    }

    __syncthreads();   // covers ss/sq init before LDS atomics
    #pragma unroll
    for (int mf = 0; mf < 4; ++mf) {
        #pragma unroll
        for (int r = 0; r < 4; ++r) {
            int o = mf*16 + lhi*4 + r;
            float bo = bt[o];
            float p = 0.f, q = 0.f;
            #pragma unroll
            for (int nf = 0; nf < 4; ++nf) {
                int tv = tv0 + wv*64 + nf*16 + l15;
                if (tv < TVsz) {
                    float val = acc[mf][nf][r] + bo;
                    ycb[((long)n*CH + o)*TVsz + tv] = f2bf(val);
                    p += val; q += val*val;
                }
            }
            p += __shfl_xor(p, 1, 64); q += __shfl_xor(q, 1, 64);
            p += __shfl_xor(p, 2, 64); q += __shfl_xor(q, 2, 64);
            p += __shfl_xor(p, 4, 64); q += __shfl_xor(q, 4, 64);
            p += __shfl_xor(p, 8, 64); q += __shfl_xor(q, 8, 64);
            if (l15 == 0) { atomicAdd(&ss[o], p); atomicAdd(&sq[o], q); }
        }
    }
    __syncthreads();
    if (tid < 64) { atomicAdd(&s1[tid], ss[tid]); atomicAdd(&s2[tid], sq[tid]); }
}

// ---------------- out = relu(bn2(yc)+x), f32 ----------------
__global__ void k_out(const float* __restrict__ x, const float* __restrict__ g2, const float* __restrict__ b2,
                      const float* __restrict__ s1, const float* __restrict__ s2,
                      const unsigned short* __restrict__ ycb, float* __restrict__ out) {
    const float invN = 1.0f / (float)PCCOUNT;
    int stride = gridDim.x * blockDim.x;
    for (int i4 = blockIdx.x*blockDim.x + threadIdx.x; i4 < TOTAL/4; i4 += stride) {
        long idx = (long)i4 * 4;
        int c = (int)((idx / TVsz) & 63);
        float m  = s1[c] * invN;
        float vr = s2[c] * invN - m*m;
        float rs = rsqrtf(vr + EPSB) * g2[c];
        float bc = b2[c];
        uint2 d = *(const uint2*)(ycb + idx);
        float4 xv = *(const float4*)(x + idx);
        float4 ov;
        ov.x = fmaxf((bf2f(d.x & 0xffffu) - m)*rs + bc + xv.x, 0.f);
        ov.y = fmaxf((bf2f(d.x >> 16)     - m)*rs + bc + xv.y, 0.f);
        ov.z = fmaxf((bf2f(d.y & 0xffffu) - m)*rs + bc + xv.z, 0.f);
        ov.w = fmaxf((bf2f(d.y >> 16)     - m)*rs + bc + xv.w, 0.f);
        *(float4*)(out + idx) = ov;
    }
}

extern "C" void kernel_launch(void* const* d_in, const int* in_sizes, int n_in,
                              void* d_out, int out_size, void* d_ws, size_t ws_size,
                              hipStream_t stream) {
    const float* x  = (const float*)d_in[0];
    const float* A  = (const float*)d_in[1];
    const float* PA = (const float*)d_in[2];
    const float* Wa = (const float*)d_in[3];
    const float* ba = (const float*)d_in[4];
    const float* Wb = (const float*)d_in[5];
    const float* bb = (const float*)d_in[6];
    const float* Wd = (const float*)d_in[7];
    const float* bd = (const float*)d_in[8];
    const float* g1 = (const float*)d_in[9];
    const float* b1 = (const float*)d_in[10];
    const float* Wt = (const float*)d_in[11];
    const float* bt = (const float*)d_in[12];
    const float* g2 = (const float*)d_in[13];
    const float* b2 = (const float*)d_in[14];

    float* ws    = (float*)d_ws;
    float* Mbuf  = ws;                                        // [0, 60000)
    float* stats = ws + 60000;                                // [60000, 60256)
    unsigned short* wdcat  = (unsigned short*)(ws + 60256);   // -> 66400
    unsigned short* wcat   = (unsigned short*)(ws + 66400);   // -> 69472
    float* biascat = ws + 69472;                              // -> 69568
    unsigned short* awT    = (unsigned short*)(ws + 69568);   // -> 88000
    unsigned short* xbt    = (unsigned short*)(ws + 88000);   // 15.36M sh -> 7768000
    unsigned short* ybuf   = (unsigned short*)(ws + 7768000); // 15.36M sh -> 15448000
    unsigned short* g_c    = (unsigned short*)(ws + 15448000);// 29.49M sh -> 30193600
    // overlays:
    unsigned short* ybt = xbt;                                // after last k_g
    unsigned short* ycb = g_c;                                // after last k_y2

    hipMemsetAsync(Mbuf, 0, (60000 + 256)*sizeof(float), stream);
    k_prep<<<217, 256, 0, stream>>>(Wt, Wd, Wa, ba, Wb, bb, awT, wdcat, wcat, biascat);
    k_xt<<<NB*118, 256, 0, stream>>>(x, xbt);
    k_attn<<<NSUB*NB*ATCN, 256, 0, stream>>>(xbt, wcat, biascat, Mbuf);
    k_softmax<<<NSUB*NB, 32, 0, stream>>>(A, PA, Mbuf);

    for (int ch = 0; ch < 2; ++ch) {
        int n0 = ch * NCHUNK;
        k_g<<<NCHUNK*NTILES, 256, 0, stream>>>(xbt + (long)n0*TVsz*CH, wdcat, g_c);
        k_y2<<<NCHUNK*320, 256, 0, stream>>>(g_c, Mbuf, bd, ybuf, stats, stats + 64, n0);
    }

    k_bn1t<<<NB*118, 256, 0, stream>>>(x, g1, b1, stats, stats + 64, ybuf, ybt);
    k_tconv<<<NB*30, 256, 0, stream>>>(ybt, awT, bt, ycb, stats + 128, stats + 192);
    k_out<<<2048, 256, 0, stream>>>(x, g2, b2, stats + 128, stats + 192, ycb, (float*)d_out);
}

// Round 6
// 338.158 us; speedup vs baseline: 1.0991x; 1.0991x over previous
//
#include <hip/hip_runtime.h>
#include <hip/hip_bf16.h>

#define NB 32
#define CH 64
#define TF 300
#define VJ 25
#define NSUB 3
#define ICB 16
#define KW 9
#define EPSB 1e-5f

#define TVsz (TF*VJ)          // 7500
#define CTVsz (CH*TF*VJ)      // 480000
#define TOTAL (NB*CTVsz)      // 15360000
#define PCCOUNT (NB*TF*VJ)    // 240000

#define NCHUNK 16             // n per chunk for g
#define NTILES 59             // ceil(7500/128) for k_g
#define ATC 32                // t per attention chunk
#define ATCN 10               // ceil(300/32)

typedef __attribute__((ext_vector_type(8))) short s16x8;
typedef __attribute__((ext_vector_type(4))) float f32x4;

__device__ __forceinline__ unsigned short f2bf(float v) {
    __hip_bfloat16 h = __float2bfloat16(v);
    return *(unsigned short*)&h;
}
__device__ __forceinline__ float bf2f(unsigned int u) {
    return __uint_as_float(u << 16);
}

// ---------------- merged weight prep ----------------
__global__ void k_prep(const float* __restrict__ Wt, const float* __restrict__ Wd,
                       const float* __restrict__ Wa, const float* __restrict__ ba,
                       const float* __restrict__ Wb, const float* __restrict__ bb,
                       unsigned short* __restrict__ awT, unsigned short* __restrict__ wdcat,
                       unsigned short* __restrict__ wcat, float* __restrict__ biascat) {
    int e = blockIdx.x * 256 + threadIdx.x;
    if (e < CH*CH*KW) {
        int o = e / (CH*KW), c = (e / KW) % CH, k = e % KW;
        awT[(k*CH + o)*CH + c] = f2bf(Wt[e]);
        return;
    }
    int e2 = e - CH*CH*KW;
    if (e2 < NSUB*CH*CH) { wdcat[e2] = f2bf(Wd[e2]); return; }
    int e3 = e2 - NSUB*CH*CH;
    if (e3 < 6144) {
        int i = e3 / 2048, rm = (e3 >> 6) & 31, c = e3 & 63;
        wcat[e3] = f2bf((rm < 16) ? Wa[(i*ICB + rm)*CH + c] : Wb[(i*ICB + rm - 16)*CH + c]);
        return;
    }
    if (e3 < 6240) {
        int j = e3 - 6144;
        int i = j >> 5, r = j & 31;
        biascat[j] = (r < 16) ? ba[i*ICB + r] : bb[i*ICB + r - 16];
    }
}

// ---------------- x transpose (all n): [n][c][tv] f32 -> [n][tv][c] bf16 ----
__global__ __launch_bounds__(256) void k_xt(const float* __restrict__ x,
                                            unsigned short* __restrict__ xbt) {
    __shared__ unsigned short ls[64*66];
    int b = blockIdx.x;
    int n = b / 118, tile = b % 118;
    int tv0 = tile * 64;
    int tid = threadIdx.x;
    const float* xg = x + (long)n * CTVsz;
    for (int e = tid; e < 1024; e += 256) {
        int c = e >> 4, t4 = (e & 15) * 4;
        int tv = tv0 + t4;
        if (tv < TVsz) {
            float4 v = *(const float4*)(xg + (long)c*TVsz + tv);
            ls[(t4+0)*66 + c] = f2bf(v.x);
            ls[(t4+1)*66 + c] = f2bf(v.y);
            ls[(t4+2)*66 + c] = f2bf(v.z);
            ls[(t4+3)*66 + c] = f2bf(v.w);
        }
    }
    __syncthreads();
    for (int e = tid; e < 1024; e += 256) {
        int tvl = e >> 4, c4 = (e & 15) * 4;
        int tv = tv0 + tvl;
        if (tv < TVsz) {
            unsigned int lo = *(const unsigned int*)&ls[tvl*66 + c4];
            unsigned int hi = *(const unsigned int*)&ls[tvl*66 + c4 + 2];
            *(uint2*)&xbt[((long)n*TVsz + tv)*CH + c4] = make_uint2(lo, hi);
        }
    }
}

// ---------------- attention: emb MFMA -> LDS -> Gram MFMA -> atomics --------
__global__ __launch_bounds__(256) void k_attn(
    const unsigned short* __restrict__ xbt, const unsigned short* __restrict__ wcat,
    const float* __restrict__ biascat, float* __restrict__ Mbuf)
{
    __shared__ __align__(16) char emb[32*32*ATC*2];
    __shared__ float gram[625];
    int b = blockIdx.x;
    int i   = b / (NB*ATCN);
    int rem = b % (NB*ATCN);
    int n = rem / ATCN, tc = rem % ATCN;
    int t0 = tc * ATC;
    int tid = threadIdx.x;
    int wv = tid >> 6, l = tid & 63, l15 = l & 15, lhi = l >> 4;

    for (int e = tid; e < 625; e += 256) gram[e] = 0.f;

    s16x8 wf[2][2];
    #pragma unroll
    for (int mf = 0; mf < 2; ++mf)
        #pragma unroll
        for (int kc = 0; kc < 2; ++kc)
            wf[mf][kc] = *(const s16x8*)(wcat + ((i*32 + mf*16 + l15)*64 + kc*32 + lhi*8));
    float bs[2][4];
    #pragma unroll
    for (int mf = 0; mf < 2; ++mf)
        #pragma unroll
        for (int r = 0; r < 4; ++r)
            bs[mf][r] = biascat[i*32 + mf*16 + lhi*4 + r];

    const unsigned short* xb = xbt + (long)n * TVsz * CH;
    for (int v = wv; v < 25; v += 4) {
        f32x4 ae[2][2];
        #pragma unroll
        for (int mf = 0; mf < 2; ++mf)
            #pragma unroll
            for (int nf = 0; nf < 2; ++nf)
                ae[mf][nf] = (f32x4){0.f,0.f,0.f,0.f};
        #pragma unroll
        for (int nf = 0; nf < 2; ++nf) {
            int t = t0 + nf*16 + l15;
            int tcl = t < TF ? t : TF-1;
            const unsigned short* bp = xb + ((long)tcl*VJ + v)*CH;
            s16x8 b0 = *(const s16x8*)(bp + lhi*8);
            s16x8 b1 = *(const s16x8*)(bp + 32 + lhi*8);
            #pragma unroll
            for (int mf = 0; mf < 2; ++mf) {
                ae[mf][nf] = __builtin_amdgcn_mfma_f32_16x16x32_bf16(wf[mf][0], b0, ae[mf][nf], 0,0,0);
                ae[mf][nf] = __builtin_amdgcn_mfma_f32_16x16x32_bf16(wf[mf][1], b1, ae[mf][nf], 0,0,0);
            }
        }
        #pragma unroll
        for (int mf = 0; mf < 2; ++mf)
            #pragma unroll
            for (int nf = 0; nf < 2; ++nf)
                #pragma unroll
                for (int r = 0; r < 4; ++r) {
                    int t  = t0 + nf*16 + l15;
                    int tl = nf*16 + l15;
                    int m  = mf*16 + lhi*4 + r;
                    float val = (t < TF) ? (ae[mf][nf][r] + bs[mf][r]) : 0.f;
                    int byte = (((v*32 + m)*ATC + tl)*2) ^ ((v&7)<<4);
                    *(unsigned short*)(emb + byte) = f2bf(val);
                }
    }
    __syncthreads();

    f32x4 ag[2][2];
    #pragma unroll
    for (int mu = 0; mu < 2; ++mu)
        #pragma unroll
        for (int nw = 0; nw < 2; ++nw)
            ag[mu][nw] = (f32x4){0.f,0.f,0.f,0.f};
    #pragma unroll
    for (int oo = 0; oo < 4; ++oo) {
        int o = wv*4 + oo;
        s16x8 fa[2], fb[2];
        #pragma unroll
        for (int mu = 0; mu < 2; ++mu) {
            int u = mu*16 + l15; if (u > 24) u = 24;
            fa[mu] = *(const s16x8*)(emb + ((((u*32 + o)*ATC + lhi*8)*2) ^ ((u&7)<<4)));
        }
        #pragma unroll
        for (int nw = 0; nw < 2; ++nw) {
            int w = nw*16 + l15; if (w > 24) w = 24;
            fb[nw] = *(const s16x8*)(emb + ((((w*32 + 16 + o)*ATC + lhi*8)*2) ^ ((w&7)<<4)));
        }
        #pragma unroll
        for (int mu = 0; mu < 2; ++mu)
            #pragma unroll
            for (int nw = 0; nw < 2; ++nw)
                ag[mu][nw] = __builtin_amdgcn_mfma_f32_16x16x32_bf16(fa[mu], fb[nw], ag[mu][nw], 0,0,0);
    }
    #pragma unroll
    for (int mu = 0; mu < 2; ++mu)
        #pragma unroll
        for (int nw = 0; nw < 2; ++nw)
            #pragma unroll
            for (int r = 0; r < 4; ++r) {
                int u = mu*16 + lhi*4 + r;
                int w = nw*16 + l15;
                if (u < 25 && w < 25)
                    atomicAdd(&gram[u*25 + w], ag[mu][nw][r]);
            }
    __syncthreads();
    for (int e = tid; e < 625; e += 256)
        atomicAdd(&Mbuf[(i*NB + n)*625 + e], gram[e]);
}

// ---------------- column softmax + A+PA ----------------
__global__ void k_softmax(const float* __restrict__ A, const float* __restrict__ PA,
                          float* __restrict__ Mbuf) {
    int b = blockIdx.x;
    int i = b / NB;
    int w = threadIdx.x;
    if (w >= 25) return;
    float* M = Mbuf + b*625;
    const float scale = 1.0f / (float)(ICB * TF);
    float col[25];
    float mx = -1e30f;
    #pragma unroll
    for (int u = 0; u < 25; ++u) { col[u] = M[u*25 + w] * scale; mx = fmaxf(mx, col[u]); }
    float s = 0.f;
    #pragma unroll
    for (int u = 0; u < 25; ++u) { col[u] = __expf(col[u] - mx); s += col[u]; }
    float inv = 1.0f / s;
    #pragma unroll
    for (int u = 0; u < 25; ++u)
        M[u*25 + w] = col[u]*inv + A[i*625 + u*25 + w] + PA[i*625 + u*25 + w];
}

// ---------------- GEMM1: g = Wdcat[192,64] x[64,7500] per n (chunk) --------
__global__ __launch_bounds__(256) void k_g(const unsigned short* __restrict__ xbt,
                                           const unsigned short* __restrict__ wdcat,
                                           unsigned short* __restrict__ g) {
    int b = blockIdx.x;
    int nc = b / NTILES, tile = b % NTILES;
    int tv0 = tile * 128;
    int tid = threadIdx.x;
    int w = tid >> 6, wm = w >> 1, wn = w & 1;
    int l = tid & 63, l15 = l & 15, lhi = l >> 4;

    s16x8 af[6][2];
    #pragma unroll
    for (int mf = 0; mf < 6; ++mf)
        #pragma unroll
        for (int kc = 0; kc < 2; ++kc)
            af[mf][kc] = *(const s16x8*)(wdcat + ((wm*96 + mf*16 + l15)*64 + kc*32 + lhi*8));

    f32x4 acc[6][4];
    #pragma unroll
    for (int mf = 0; mf < 6; ++mf)
        #pragma unroll
        for (int nf = 0; nf < 4; ++nf)
            acc[mf][nf] = (f32x4){0.f,0.f,0.f,0.f};

    const unsigned short* xb = xbt + (long)nc * TVsz * CH;
    #pragma unroll
    for (int nf = 0; nf < 4; ++nf) {
        int tv = tv0 + wn*64 + nf*16 + l15;
        int tvc = tv < TVsz ? tv : TVsz-1;
        s16x8 b0 = *(const s16x8*)(xb + (long)tvc*CH + lhi*8);
        s16x8 b1 = *(const s16x8*)(xb + (long)tvc*CH + 32 + lhi*8);
        #pragma unroll
        for (int mf = 0; mf < 6; ++mf) {
            acc[mf][nf] = __builtin_amdgcn_mfma_f32_16x16x32_bf16(af[mf][0], b0, acc[mf][nf], 0,0,0);
            acc[mf][nf] = __builtin_amdgcn_mfma_f32_16x16x32_bf16(af[mf][1], b1, acc[mf][nf], 0,0,0);
        }
    }

    #pragma unroll
    for (int nf = 0; nf < 4; ++nf) {
        int tv = tv0 + wn*64 + nf*16 + l15;
        if (tv < TVsz) {
            int t = tv / 25, u = tv % 25;
            #pragma unroll
            for (int mf = 0; mf < 6; ++mf) {
                #pragma unroll
                for (int r = 0; r < 4; ++r) {
                    int m = wm*96 + mf*16 + lhi*4 + r;
                    long base = (((long)nc*192 + m)*TF + t)*32;
                    g[base + u] = f2bf(acc[mf][nf][r]);
                    if (u == 24) {
                        #pragma unroll
                        for (int p = 25; p < 32; ++p) g[base + p] = 0;
                    }
                }
            }
        }
    }
}

// -------- GEMM2 + fused BN1 partial stats: y (bf16) = sum_i g*attn + bd -----
__global__ __launch_bounds__(256) void k_y2(const unsigned short* __restrict__ g,
                                            const float* __restrict__ Mbuf,
                                            const float* __restrict__ bd,
                                            unsigned short* __restrict__ ybuf,
                                            float* __restrict__ s1, float* __restrict__ s2,
                                            int n0) {
    __shared__ unsigned short attnT[32][104];
    __shared__ float sp[4], sq[4];
    int b = blockIdx.x;
    int nc = b / 320;
    int rem = b % 320;
    int o = rem / 5, tb = rem % 5;
    int n = n0 + nc;
    int tid = threadIdx.x;

    for (int e = tid; e < 32*104; e += 256) ((unsigned short*)attnT)[e] = 0;
    __syncthreads();
    for (int e = tid; e < 3*625; e += 256) {
        int i = e / 625, uw = e % 625;
        int u = uw / 25, v = uw % 25;
        attnT[v][i*32 + u] = f2bf(Mbuf[(i*NB + n)*625 + uw]);
    }
    __syncthreads();

    int w = tid >> 6, l = tid & 63, l15 = l & 15, lhi = l >> 4;
    int t0 = tb*64 + w*16;

    f32x4 acc[2];
    acc[0] = (f32x4){0.f,0.f,0.f,0.f};
    acc[1] = (f32x4){0.f,0.f,0.f,0.f};

    #pragma unroll
    for (int kc = 0; kc < 3; ++kc) {
        int t = t0 + l15; if (t > 299) t = 299;
        s16x8 a = *(const s16x8*)(g + ((((long)nc*192 + kc*64 + o)*TF + t)*32 + lhi*8));
        #pragma unroll
        for (int nf = 0; nf < 2; ++nf) {
            s16x8 bfr = *(const s16x8*)(&attnT[nf*16 + l15][kc*32 + lhi*8]);
            acc[nf] = __builtin_amdgcn_mfma_f32_16x16x32_bf16(a, bfr, acc[nf], 0,0,0);
        }
    }

    float bds = bd[o] + bd[CH + o] + bd[2*CH + o];
    float p = 0.f, q = 0.f;
    #pragma unroll
    for (int nf = 0; nf < 2; ++nf) {
        #pragma unroll
        for (int r = 0; r < 4; ++r) {
            int t = t0 + lhi*4 + r;
            int v = nf*16 + l15;
            if (t < TF && v < VJ) {
                float val = acc[nf][r] + bds;
                ybuf[((long)n*CH + o)*TVsz + t*25 + v] = f2bf(val);
                p += val; q += val*val;
            }
        }
    }
    #pragma unroll
    for (int m = 1; m < 64; m <<= 1) {
        p += __shfl_xor(p, m, 64);
        q += __shfl_xor(q, m, 64);
    }
    if (l == 0) { sp[w] = p; sq[w] = q; }
    __syncthreads();
    if (tid == 0) {
        atomicAdd(&s1[o], sp[0]+sp[1]+sp[2]+sp[3]);
        atomicAdd(&s2[o], sq[0]+sq[1]+sq[2]+sq[3]);
    }
}

// ------ y = relu(bn1(y)+x) -> bf16, t-major layout [n][v][t][c] -------------
__global__ __launch_bounds__(256) void k_bn1t(
    const float* __restrict__ x, const float* __restrict__ g1, const float* __restrict__ b1,
    const float* __restrict__ s1, const float* __restrict__ s2,
    const unsigned short* __restrict__ yb, unsigned short* __restrict__ ybt)
{
    __shared__ unsigned short ls[64*66];
    int b = blockIdx.x;
    int n = b / 118, tile = b % 118;
    int tv0 = tile * 64;
    const float invN = 1.0f / (float)PCCOUNT;
    int tid = threadIdx.x;

    for (int e = tid; e < 1024; e += 256) {
        int c = e >> 4, t4 = (e & 15) * 4;
        int tv = tv0 + t4;
        if (tv < TVsz) {
            long gbase = (long)n*CTVsz + (long)c*TVsz;
            float m  = s1[c] * invN;
            float vr = s2[c] * invN - m*m;
            float sc = rsqrtf(vr + EPSB) * g1[c];
            float bc = b1[c];
            uint2 yv = *(const uint2*)(yb + gbase + tv);
            float4 xv = *(const float4*)(x + gbase + tv);
            ls[(t4+0)*66 + c] = f2bf(fmaxf((bf2f(yv.x & 0xffffu) - m)*sc + bc + xv.x, 0.f));
            ls[(t4+1)*66 + c] = f2bf(fmaxf((bf2f(yv.x >> 16)     - m)*sc + bc + xv.y, 0.f));
            ls[(t4+2)*66 + c] = f2bf(fmaxf((bf2f(yv.y & 0xffffu) - m)*sc + bc + xv.z, 0.f));
            ls[(t4+3)*66 + c] = f2bf(fmaxf((bf2f(yv.y >> 16)     - m)*sc + bc + xv.w, 0.f));
        }
    }
    __syncthreads();
    for (int e = tid; e < 1024; e += 256) {
        int tvl = e >> 4, c4 = (e & 15) * 4;
        int tv = tv0 + tvl;
        if (tv < TVsz) {
            int v = tv % 25, t = tv / 25;
            unsigned int lo = *(const unsigned int*)&ls[tvl*66 + c4];
            unsigned int hi = *(const unsigned int*)&ls[tvl*66 + c4 + 2];
            *(uint2*)&ybt[(((long)n*VJ + v)*TF + t)*CH + c4] = make_uint2(lo, hi);
        }
    }
}

// ------- temporal conv via MFMA on [n][v][t][c], fused BN2 partial stats ----
// block = (n, v, t-half); LDS tile = 168 rows x 128 B (4+160+4 halo), swizzled
#define TT 150
#define TROWS 168

__global__ __launch_bounds__(256) void k_tconv(
    const unsigned short* __restrict__ ybt, const unsigned short* __restrict__ awT,
    const float* __restrict__ bt, unsigned short* __restrict__ ycb,
    float* __restrict__ s1, float* __restrict__ s2)
{
    __shared__ __align__(16) char ys[TROWS*128];
    __shared__ float ss[64], sq[64];
    int b = blockIdx.x;
    int n = b / 50, rem = b % 50;
    int v = rem >> 1, th = rem & 1;
    int t0 = th * TT;
    int tid = threadIdx.x;
    int wv = tid >> 6, l = tid & 63, l15 = l & 15, lhi = l >> 4;
    if (tid < 64) { ss[tid] = 0.f; sq[tid] = 0.f; }

    // stage rows t0-4 .. t0+163 (contiguous in t-major layout)
    const char* src = (const char*)(ybt + (((long)n*VJ + v)*TF)*CH);
    for (int qq = tid; qq < TROWS*8; qq += 256) {
        int row = qq >> 3;
        int cb  = (qq & 7) << 4;
        int tg = t0 - 4 + row;
        uint4 val = make_uint4(0u,0u,0u,0u);
        if (tg >= 0 && tg < TF)
            val = *(const uint4*)(src + (long)tg*128 + cb);
        *(uint4*)(ys + row*128 + (cb ^ ((row & 7) << 4))) = val;
    }
    __syncthreads();

    int og  = (wv & 1) * 32;      // o-base of this wave (32 o's)
    int wt0 = (wv >> 1) * 80;     // t-base within half (80 t's)
    const short* aw = (const short*)awT;

    f32x4 acc[2][5];
    #pragma unroll
    for (int mf = 0; mf < 2; ++mf)
        #pragma unroll
        for (int nf = 0; nf < 5; ++nf)
            acc[mf][nf] = (f32x4){0.f,0.f,0.f,0.f};

    for (int tap = 0; tap < KW; ++tap) {
        #pragma unroll
        for (int kc = 0; kc < 2; ++kc) {
            s16x8 af[2], bfr[5];
            #pragma unroll
            for (int mf = 0; mf < 2; ++mf)
                af[mf] = *(const s16x8*)(aw + ((tap*CH + og + mf*16 + l15)*CH + kc*32 + lhi*8));
            #pragma unroll
            for (int nf = 0; nf < 5; ++nf) {
                int rloc = wt0 + nf*16 + l15 + tap;   // in [0, 168)
                int cb = (kc*64 + lhi*16) ^ ((rloc & 7) << 4);
                bfr[nf] = *(const s16x8*)(ys + rloc*128 + cb);
            }
            #pragma unroll
            for (int mf = 0; mf < 2; ++mf)
                #pragma unroll
                for (int nf = 0; nf < 5; ++nf)
                    acc[mf][nf] = __builtin_amdgcn_mfma_f32_16x16x32_bf16(
                        af[mf], bfr[nf], acc[mf][nf], 0, 0, 0);
        }
    }

    #pragma unroll
    for (int mf = 0; mf < 2; ++mf) {
        #pragma unroll
        for (int r = 0; r < 4; ++r) {
            int o = og + mf*16 + lhi*4 + r;
            float bo = bt[o];
            float p = 0.f, q = 0.f;
            #pragma unroll
            for (int nf = 0; nf < 5; ++nf) {
                int tl = wt0 + nf*16 + l15;
                if (tl < TT) {
                    float val = acc[mf][nf][r] + bo;
                    ycb[(((long)n*CH + o)*VJ + v)*TF + t0 + tl] = f2bf(val);
                    p += val; q += val*val;
                }
            }
            p += __shfl_xor(p, 1, 64); q += __shfl_xor(q, 1, 64);
            p += __shfl_xor(p, 2, 64); q += __shfl_xor(q, 2, 64);
            p += __shfl_xor(p, 4, 64); q += __shfl_xor(q, 4, 64);
            p += __shfl_xor(p, 8, 64); q += __shfl_xor(q, 8, 64);
            if (l15 == 0) { atomicAdd(&ss[o], p); atomicAdd(&sq[o], q); }
        }
    }
    __syncthreads();
    if (tid < 64) { atomicAdd(&s1[tid], ss[tid]); atomicAdd(&s2[tid], sq[tid]); }
}

// ------- out = relu(bn2(yc)+x): block=(n,c), LDS v<->t transpose ------------
__global__ __launch_bounds__(256) void k_out(
    const float* __restrict__ x, const float* __restrict__ g2, const float* __restrict__ b2,
    const float* __restrict__ s1, const float* __restrict__ s2,
    const unsigned short* __restrict__ ycb, float* __restrict__ out)
{
    __shared__ float ls[VJ*305];   // [v][t], stride 305 (coprime 32 banks)
    const float invN = 1.0f / (float)PCCOUNT;
    int b = blockIdx.x;
    int n = b >> 6, c = b & 63;
    int tid = threadIdx.x;

    float m  = s1[c] * invN;
    float vr = s2[c] * invN - m*m;
    float rs = rsqrtf(vr + EPSB) * g2[c];
    float bc = b2[c];

    const uint2* yc = (const uint2*)(ycb + ((long)n*CH + c)*TVsz);   // [v][t] order
    for (int e = tid; e < TVsz/4; e += 256) {
        uint2 d = yc[e];
        int base = e*4;              // = v*300 + t4 (300 % 4 == 0 -> same v)
        int v = base / TF, t = base % TF;
        float* lp = &ls[v*305 + t];
        lp[0] = (bf2f(d.x & 0xffffu) - m)*rs + bc;
        lp[1] = (bf2f(d.x >> 16)     - m)*rs + bc;
        lp[2] = (bf2f(d.y & 0xffffu) - m)*rs + bc;
        lp[3] = (bf2f(d.y >> 16)     - m)*rs + bc;
    }
    __syncthreads();

    long gbase = ((long)n*CH + c)*TVsz;
    for (int e = tid; e < TVsz/4; e += 256) {
        int tv = e*4;
        float4 xv = *(const float4*)(x + gbase + tv);
        float4 ov;
        {
            int v = (tv+0) % 25, t = (tv+0) / 25;
            ov.x = fmaxf(ls[v*305 + t] + xv.x, 0.f);
        }
        {
            int v = (tv+1) % 25, t = (tv+1) / 25;
            ov.y = fmaxf(ls[v*305 + t] + xv.y, 0.f);
        }
        {
            int v = (tv+2) % 25, t = (tv+2) / 25;
            ov.z = fmaxf(ls[v*305 + t] + xv.z, 0.f);
        }
        {
            int v = (tv+3) % 25, t = (tv+3) / 25;
            ov.w = fmaxf(ls[v*305 + t] + xv.w, 0.f);
        }
        *(float4*)(out + gbase + tv) = ov;
    }
}

extern "C" void kernel_launch(void* const* d_in, const int* in_sizes, int n_in,
                              void* d_out, int out_size, void* d_ws, size_t ws_size,
                              hipStream_t stream) {
    const float* x  = (const float*)d_in[0];
    const float* A  = (const float*)d_in[1];
    const float* PA = (const float*)d_in[2];
    const float* Wa = (const float*)d_in[3];
    const float* ba = (const float*)d_in[4];
    const float* Wb = (const float*)d_in[5];
    const float* bb = (const float*)d_in[6];
    const float* Wd = (const float*)d_in[7];
    const float* bd = (const float*)d_in[8];
    const float* g1 = (const float*)d_in[9];
    const float* b1 = (const float*)d_in[10];
    const float* Wt = (const float*)d_in[11];
    const float* bt = (const float*)d_in[12];
    const float* g2 = (const float*)d_in[13];
    const float* b2 = (const float*)d_in[14];

    float* ws    = (float*)d_ws;
    float* Mbuf  = ws;                                        // [0, 60000)
    float* stats = ws + 60000;                                // [60000, 60256)
    unsigned short* wdcat  = (unsigned short*)(ws + 60256);   // -> 66400
    unsigned short* wcat   = (unsigned short*)(ws + 66400);   // -> 69472
    float* biascat = ws + 69472;                              // -> 69568
    unsigned short* awT    = (unsigned short*)(ws + 69568);   // -> 88000
    unsigned short* xbt    = (unsigned short*)(ws + 88000);   // 15.36M sh -> 7768000
    unsigned short* ybuf   = (unsigned short*)(ws + 7768000); // 15.36M sh -> 15448000
    unsigned short* g_c    = (unsigned short*)(ws + 15448000);// 29.49M sh -> 30193600
    // overlays:
    unsigned short* ybt = xbt;                                // after last k_g
    unsigned short* ycb = g_c;                                // after last k_y2

    hipMemsetAsync(Mbuf, 0, (60000 + 256)*sizeof(float), stream);
    k_prep<<<217, 256, 0, stream>>>(Wt, Wd, Wa, ba, Wb, bb, awT, wdcat, wcat, biascat);
    k_xt<<<NB*118, 256, 0, stream>>>(x, xbt);
    k_attn<<<NSUB*NB*ATCN, 256, 0, stream>>>(xbt, wcat, biascat, Mbuf);
    k_softmax<<<NSUB*NB, 32, 0, stream>>>(A, PA, Mbuf);

    for (int ch = 0; ch < 2; ++ch) {
        int n0 = ch * NCHUNK;
        k_g<<<NCHUNK*NTILES, 256, 0, stream>>>(xbt + (long)n0*TVsz*CH, wdcat, g_c);
        k_y2<<<NCHUNK*320, 256, 0, stream>>>(g_c, Mbuf, bd, ybuf, stats, stats + 64, n0);
    }

    k_bn1t<<<NB*118, 256, 0, stream>>>(x, g1, b1, stats, stats + 64, ybuf, ybt);
    k_tconv<<<NB*50, 256, 0, stream>>>(ybt, awT, bt, ycb, stats + 128, stats + 192);
    k_out<<<NB*CH, 256, 0, stream>>>(x, g2, b2, stats + 128, stats + 192, ycb, (float*)d_out);
}

// Round 7
// 279.958 us; speedup vs baseline: 1.3276x; 1.2079x over previous
//
#include <hip/hip_runtime.h>
#include <hip/hip_bf16.h>

#define NB 32
#define CH 64
#define TF 300
#define VJ 25
#define NSUB 3
#define ICB 16
#define KW 9
#define EPSB 1e-5f

#define TVsz (TF*VJ)          // 7500
#define CTVsz (CH*TF*VJ)      // 480000
#define TOTAL (NB*CTVsz)      // 15360000
#define PCCOUNT (NB*TF*VJ)    // 240000

#define ATC 32                // t per attention chunk
#define ATCN 10               // ceil(300/32)

typedef __attribute__((ext_vector_type(8))) short s16x8;
typedef __attribute__((ext_vector_type(4))) float f32x4;

__device__ __forceinline__ unsigned short f2bf(float v) {
    __hip_bfloat16 h = __float2bfloat16(v);
    return *(unsigned short*)&h;
}
__device__ __forceinline__ float bf2f(unsigned int u) {
    return __uint_as_float(u << 16);
}

// ---------------- merged weight prep ----------------
__global__ void k_prep(const float* __restrict__ Wt, const float* __restrict__ Wd,
                       const float* __restrict__ Wa, const float* __restrict__ ba,
                       const float* __restrict__ Wb, const float* __restrict__ bb,
                       unsigned short* __restrict__ awT, unsigned short* __restrict__ wdcat,
                       unsigned short* __restrict__ wcat, float* __restrict__ biascat) {
    int e = blockIdx.x * 256 + threadIdx.x;
    if (e < CH*CH*KW) {
        int o = e / (CH*KW), c = (e / KW) % CH, k = e % KW;
        awT[(k*CH + o)*CH + c] = f2bf(Wt[e]);
        return;
    }
    int e2 = e - CH*CH*KW;
    if (e2 < NSUB*CH*CH) { wdcat[e2] = f2bf(Wd[e2]); return; }
    int e3 = e2 - NSUB*CH*CH;
    if (e3 < 6144) {
        int i = e3 / 2048, rm = (e3 >> 6) & 31, c = e3 & 63;
        wcat[e3] = f2bf((rm < 16) ? Wa[(i*ICB + rm)*CH + c] : Wb[(i*ICB + rm - 16)*CH + c]);
        return;
    }
    if (e3 < 6240) {
        int j = e3 - 6144;
        int i = j >> 5, r = j & 31;
        biascat[j] = (r < 16) ? ba[i*ICB + r] : bb[i*ICB + r - 16];
    }
}

// ---------------- x transpose (all n): [n][c][tv] f32 -> [n][tv][c] bf16 ----
__global__ __launch_bounds__(256) void k_xt(const float* __restrict__ x,
                                            unsigned short* __restrict__ xbt) {
    __shared__ unsigned short ls[64*66];
    int b = blockIdx.x;
    int n = b / 118, tile = b % 118;
    int tv0 = tile * 64;
    int tid = threadIdx.x;
    const float* xg = x + (long)n * CTVsz;
    for (int e = tid; e < 1024; e += 256) {
        int c = e >> 4, t4 = (e & 15) * 4;
        int tv = tv0 + t4;
        if (tv < TVsz) {
            float4 v = *(const float4*)(xg + (long)c*TVsz + tv);
            ls[(t4+0)*66 + c] = f2bf(v.x);
            ls[(t4+1)*66 + c] = f2bf(v.y);
            ls[(t4+2)*66 + c] = f2bf(v.z);
            ls[(t4+3)*66 + c] = f2bf(v.w);
        }
    }
    __syncthreads();
    for (int e = tid; e < 1024; e += 256) {
        int tvl = e >> 4, c4 = (e & 15) * 4;
        int tv = tv0 + tvl;
        if (tv < TVsz) {
            unsigned int lo = *(const unsigned int*)&ls[tvl*66 + c4];
            unsigned int hi = *(const unsigned int*)&ls[tvl*66 + c4 + 2];
            *(uint2*)&xbt[((long)n*TVsz + tv)*CH + c4] = make_uint2(lo, hi);
        }
    }
}

// ---------------- attention: emb MFMA -> LDS -> Gram MFMA -> atomics --------
__global__ __launch_bounds__(256) void k_attn(
    const unsigned short* __restrict__ xbt, const unsigned short* __restrict__ wcat,
    const float* __restrict__ biascat, float* __restrict__ Mbuf)
{
    __shared__ __align__(16) char emb[32*32*ATC*2];
    __shared__ float gram[625];
    int b = blockIdx.x;
    int i   = b / (NB*ATCN);
    int rem = b % (NB*ATCN);
    int n = rem / ATCN, tc = rem % ATCN;
    int t0 = tc * ATC;
    int tid = threadIdx.x;
    int wv = tid >> 6, l = tid & 63, l15 = l & 15, lhi = l >> 4;

    for (int e = tid; e < 625; e += 256) gram[e] = 0.f;

    s16x8 wf[2][2];
    #pragma unroll
    for (int mf = 0; mf < 2; ++mf)
        #pragma unroll
        for (int kc = 0; kc < 2; ++kc)
            wf[mf][kc] = *(const s16x8*)(wcat + ((i*32 + mf*16 + l15)*64 + kc*32 + lhi*8));
    float bs[2][4];
    #pragma unroll
    for (int mf = 0; mf < 2; ++mf)
        #pragma unroll
        for (int r = 0; r < 4; ++r)
            bs[mf][r] = biascat[i*32 + mf*16 + lhi*4 + r];

    const unsigned short* xb = xbt + (long)n * TVsz * CH;
    for (int v = wv; v < 25; v += 4) {
        f32x4 ae[2][2];
        #pragma unroll
        for (int mf = 0; mf < 2; ++mf)
            #pragma unroll
            for (int nf = 0; nf < 2; ++nf)
                ae[mf][nf] = (f32x4){0.f,0.f,0.f,0.f};
        #pragma unroll
        for (int nf = 0; nf < 2; ++nf) {
            int t = t0 + nf*16 + l15;
            int tcl = t < TF ? t : TF-1;
            const unsigned short* bp = xb + ((long)tcl*VJ + v)*CH;
            s16x8 b0 = *(const s16x8*)(bp + lhi*8);
            s16x8 b1 = *(const s16x8*)(bp + 32 + lhi*8);
            #pragma unroll
            for (int mf = 0; mf < 2; ++mf) {
                ae[mf][nf] = __builtin_amdgcn_mfma_f32_16x16x32_bf16(wf[mf][0], b0, ae[mf][nf], 0,0,0);
                ae[mf][nf] = __builtin_amdgcn_mfma_f32_16x16x32_bf16(wf[mf][1], b1, ae[mf][nf], 0,0,0);
            }
        }
        #pragma unroll
        for (int mf = 0; mf < 2; ++mf)
            #pragma unroll
            for (int nf = 0; nf < 2; ++nf)
                #pragma unroll
                for (int r = 0; r < 4; ++r) {
                    int t  = t0 + nf*16 + l15;
                    int tl = nf*16 + l15;
                    int m  = mf*16 + lhi*4 + r;
                    float val = (t < TF) ? (ae[mf][nf][r] + bs[mf][r]) : 0.f;
                    int byte = (((v*32 + m)*ATC + tl)*2) ^ ((v&7)<<4);
                    *(unsigned short*)(emb + byte) = f2bf(val);
                }
    }
    __syncthreads();

    f32x4 ag[2][2];
    #pragma unroll
    for (int mu = 0; mu < 2; ++mu)
        #pragma unroll
        for (int nw = 0; nw < 2; ++nw)
            ag[mu][nw] = (f32x4){0.f,0.f,0.f,0.f};
    #pragma unroll
    for (int oo = 0; oo < 4; ++oo) {
        int o = wv*4 + oo;
        s16x8 fa[2], fb[2];
        #pragma unroll
        for (int mu = 0; mu < 2; ++mu) {
            int u = mu*16 + l15; if (u > 24) u = 24;
            fa[mu] = *(const s16x8*)(emb + ((((u*32 + o)*ATC + lhi*8)*2) ^ ((u&7)<<4)));
        }
        #pragma unroll
        for (int nw = 0; nw < 2; ++nw) {
            int w = nw*16 + l15; if (w > 24) w = 24;
            fb[nw] = *(const s16x8*)(emb + ((((w*32 + 16 + o)*ATC + lhi*8)*2) ^ ((w&7)<<4)));
        }
        #pragma unroll
        for (int mu = 0; mu < 2; ++mu)
            #pragma unroll
            for (int nw = 0; nw < 2; ++nw)
                ag[mu][nw] = __builtin_amdgcn_mfma_f32_16x16x32_bf16(fa[mu], fb[nw], ag[mu][nw], 0,0,0);
    }
    #pragma unroll
    for (int mu = 0; mu < 2; ++mu)
        #pragma unroll
        for (int nw = 0; nw < 2; ++nw)
            #pragma unroll
            for (int r = 0; r < 4; ++r) {
                int u = mu*16 + lhi*4 + r;
                int w = nw*16 + l15;
                if (u < 25 && w < 25)
                    atomicAdd(&gram[u*25 + w], ag[mu][nw][r]);
            }
    __syncthreads();
    for (int e = tid; e < 625; e += 256)
        atomicAdd(&Mbuf[(i*NB + n)*625 + e], gram[e]);
}

// ---------------- column softmax + A+PA ----------------
__global__ void k_softmax(const float* __restrict__ A, const float* __restrict__ PA,
                          float* __restrict__ Mbuf) {
    int b = blockIdx.x;
    int i = b / NB;
    int w = threadIdx.x;
    if (w >= 25) return;
    float* M = Mbuf + b*625;
    const float scale = 1.0f / (float)(ICB * TF);
    float col[25];
    float mx = -1e30f;
    #pragma unroll
    for (int u = 0; u < 25; ++u) { col[u] = M[u*25 + w] * scale; mx = fmaxf(mx, col[u]); }
    float s = 0.f;
    #pragma unroll
    for (int u = 0; u < 25; ++u) { col[u] = __expf(col[u] - mx); s += col[u]; }
    float inv = 1.0f / s;
    #pragma unroll
    for (int u = 0; u < 25; ++u)
        M[u*25 + w] = col[u]*inv + A[i*625 + u*25 + w] + PA[i*625 + u*25 + w];
}

// ---- fused y: per (n, 4t) block, z_i = x·attn_i then y += Wd_i·z_i, BN1 stats ----
// wave w owns t = tq*4 + w. GEMM1: zT[v][c] = attnT_i[v][u] * xs[c][t][u] (K=u)
// GEMM2: y[o][v] += Wd_i[o][c] * zT[v][c] (K=c). zT per-wave -> no barriers in loop.
__global__ __launch_bounds__(256) void k_yz(
    const float* __restrict__ x, const float* __restrict__ Mbuf,
    const unsigned short* __restrict__ wdcat, const float* __restrict__ bd,
    unsigned short* __restrict__ ybuf, float* __restrict__ s1, float* __restrict__ s2)
{
    __shared__ __align__(16) char xs[64*256];               // [c][4t][32u] bf16, swizzled
    __shared__ __align__(16) unsigned short attnT[NSUB][32][40];  // zero-padded
    __shared__ __align__(16) char zT[4][32*144];            // per-wave [32v][72c] bf16
    __shared__ float ss[64], sq[64];

    int b = blockIdx.x;
    int n = b / 75, tq = b % 75;
    int tid = threadIdx.x;
    int wv = tid >> 6, l = tid & 63, l15 = l & 15, lhi = l >> 4;

    if (tid < 64) { ss[tid] = 0.f; sq[tid] = 0.f; }
    for (int e = tid; e < NSUB*32*40; e += 256) ((unsigned short*)attnT)[e] = 0;
    __syncthreads();
    for (int e = tid; e < NSUB*625; e += 256) {
        int i = e / 625, uw = e % 625, u = uw / 25, v = uw % 25;
        attnT[i][v][u] = f2bf(Mbuf[(i*NB + n)*625 + uw]);
    }
    // stage x tile: [c][t][u] with u padded to 32, XOR swizzle on byte addr
    const float* xg = x + (long)n*CTVsz + tq*100;
    for (int e = tid; e < 1600; e += 256) {
        int c = e / 25, j4 = (e % 25) * 4;
        float4 vx = *(const float4*)(xg + (long)c*TVsz + j4);
        #pragma unroll
        for (int jj = 0; jj < 4; ++jj) {
            int tvv = j4 + jj;
            int t = tvv / 25, u = tvv % 25;
            float f = jj==0 ? vx.x : jj==1 ? vx.y : jj==2 ? vx.z : vx.w;
            int byte = (c*256 + t*64 + u*2) ^ ((c&7)<<4);
            *(unsigned short*)(xs + byte) = f2bf(f);
        }
    }
    // zero the u=25..31 pad (uninit LDS could be NaN; 0*NaN propagates)
    for (int e = tid; e < 64*4*7; e += 256) {
        int c = e / 28, r = e % 28, t = r / 7, u = 25 + r % 7;
        int byte = (c*256 + t*64 + u*2) ^ ((c&7)<<4);
        *(unsigned short*)(xs + byte) = 0;
    }
    __syncthreads();

    char* z = zT[wv];
    unsigned short* zp = (unsigned short*)z;

    f32x4 acc2[4][2];
    #pragma unroll
    for (int mf = 0; mf < 4; ++mf)
        #pragma unroll
        for (int nf = 0; nf < 2; ++nf)
            acc2[mf][nf] = (f32x4){0.f,0.f,0.f,0.f};

    const f32x4 z4 = (f32x4){0.f,0.f,0.f,0.f};
    for (int i = 0; i < NSUB; ++i) {
        // GEMM1: M=v(32), N=c(64), K=u(32)
        s16x8 af1[2];
        #pragma unroll
        for (int mf = 0; mf < 2; ++mf)
            af1[mf] = *(const s16x8*)((const char*)attnT + i*2560 + (mf*16 + l15)*80 + lhi*16);
        f32x4 a1[2][4];
        #pragma unroll
        for (int nf = 0; nf < 4; ++nf) {
            int c = nf*16 + l15;
            s16x8 bf1 = *(const s16x8*)(xs + ((c*256 + wv*64 + lhi*16) ^ ((c&7)<<4)));
            #pragma unroll
            for (int mf = 0; mf < 2; ++mf)
                a1[mf][nf] = __builtin_amdgcn_mfma_f32_16x16x32_bf16(af1[mf], bf1, z4, 0,0,0);
        }
        // scatter z fragments to per-wave zT[v][c]
        #pragma unroll
        for (int mf = 0; mf < 2; ++mf)
            #pragma unroll
            for (int nf = 0; nf < 4; ++nf)
                #pragma unroll
                for (int r = 0; r < 4; ++r)
                    zp[(mf*16 + lhi*4 + r)*72 + nf*16 + l15] = f2bf(a1[mf][nf][r]);
        // GEMM2: M=o(64), N=v(32), K=c(64); acc over i
        #pragma unroll
        for (int kc = 0; kc < 2; ++kc) {
            s16x8 bf2[2];
            #pragma unroll
            for (int nf = 0; nf < 2; ++nf)
                bf2[nf] = *(const s16x8*)(z + (nf*16 + l15)*144 + kc*64 + lhi*16);
            #pragma unroll
            for (int mf = 0; mf < 4; ++mf) {
                s16x8 af2 = *(const s16x8*)(wdcat + ((i*CH + mf*16 + l15)*CH + kc*32 + lhi*8));
                #pragma unroll
                for (int nf = 0; nf < 2; ++nf)
                    acc2[mf][nf] = __builtin_amdgcn_mfma_f32_16x16x32_bf16(af2, bf2[nf], acc2[mf][nf], 0,0,0);
            }
        }
    }

    int tg = tq*4 + wv;
    #pragma unroll
    for (int mf = 0; mf < 4; ++mf) {
        #pragma unroll
        for (int r = 0; r < 4; ++r) {
            int o = mf*16 + lhi*4 + r;
            float bds = bd[o] + bd[CH + o] + bd[2*CH + o];
            float p = 0.f, q = 0.f;
            #pragma unroll
            for (int nf = 0; nf < 2; ++nf) {
                int v = nf*16 + l15;
                if (v < VJ) {
                    float val = acc2[mf][nf][r] + bds;
                    ybuf[((long)n*CH + o)*TVsz + tg*25 + v] = f2bf(val);
                    p += val; q += val*val;
                }
            }
            p += __shfl_xor(p, 1, 64); q += __shfl_xor(q, 1, 64);
            p += __shfl_xor(p, 2, 64); q += __shfl_xor(q, 2, 64);
            p += __shfl_xor(p, 4, 64); q += __shfl_xor(q, 4, 64);
            p += __shfl_xor(p, 8, 64); q += __shfl_xor(q, 8, 64);
            if (l15 == 0) { atomicAdd(&ss[o], p); atomicAdd(&sq[o], q); }
        }
    }
    __syncthreads();
    if (tid < 64) { atomicAdd(&s1[tid], ss[tid]); atomicAdd(&s2[tid], sq[tid]); }
}

// ------ y = relu(bn1(y)+x) -> bf16, t-major layout [n][v][t][c] -------------
__global__ __launch_bounds__(256) void k_bn1t(
    const float* __restrict__ x, const float* __restrict__ g1, const float* __restrict__ b1,
    const float* __restrict__ s1, const float* __restrict__ s2,
    const unsigned short* __restrict__ yb, unsigned short* __restrict__ ybt)
{
    __shared__ unsigned short ls[64*66];
    int b = blockIdx.x;
    int n = b / 118, tile = b % 118;
    int tv0 = tile * 64;
    const float invN = 1.0f / (float)PCCOUNT;
    int tid = threadIdx.x;

    for (int e = tid; e < 1024; e += 256) {
        int c = e >> 4, t4 = (e & 15) * 4;
        int tv = tv0 + t4;
        if (tv < TVsz) {
            long gbase = (long)n*CTVsz + (long)c*TVsz;
            float m  = s1[c] * invN;
            float vr = s2[c] * invN - m*m;
            float sc = rsqrtf(vr + EPSB) * g1[c];
            float bc = b1[c];
            uint2 yv = *(const uint2*)(yb + gbase + tv);
            float4 xv = *(const float4*)(x + gbase + tv);
            ls[(t4+0)*66 + c] = f2bf(fmaxf((bf2f(yv.x & 0xffffu) - m)*sc + bc + xv.x, 0.f));
            ls[(t4+1)*66 + c] = f2bf(fmaxf((bf2f(yv.x >> 16)     - m)*sc + bc + xv.y, 0.f));
            ls[(t4+2)*66 + c] = f2bf(fmaxf((bf2f(yv.y & 0xffffu) - m)*sc + bc + xv.z, 0.f));
            ls[(t4+3)*66 + c] = f2bf(fmaxf((bf2f(yv.y >> 16)     - m)*sc + bc + xv.w, 0.f));
        }
    }
    __syncthreads();
    for (int e = tid; e < 1024; e += 256) {
        int tvl = e >> 4, c4 = (e & 15) * 4;
        int tv = tv0 + tvl;
        if (tv < TVsz) {
            int v = tv % 25, t = tv / 25;
            unsigned int lo = *(const unsigned int*)&ls[tvl*66 + c4];
            unsigned int hi = *(const unsigned int*)&ls[tvl*66 + c4 + 2];
            *(uint2*)&ybt[(((long)n*VJ + v)*TF + t)*CH + c4] = make_uint2(lo, hi);
        }
    }
}

// ------- temporal conv: block=(n,v), full t, 4 waves x acc[4][5], BN2 stats ----
#define TCROWS 316

__global__ __launch_bounds__(256) void k_tconv(
    const unsigned short* __restrict__ ybt, const unsigned short* __restrict__ awT,
    const float* __restrict__ bt, unsigned short* __restrict__ ycb,
    float* __restrict__ s1, float* __restrict__ s2)
{
    __shared__ __align__(16) char ys[TCROWS*128];   // 40.4 KB, XOR-swizzled
    __shared__ float ss[64], sq[64];
    int b = blockIdx.x;
    int n = b / VJ, v = b % VJ;
    int tid = threadIdx.x;
    int wv = tid >> 6, l = tid & 63, l15 = l & 15, lhi = l >> 4;
    if (tid < 64) { ss[tid] = 0.f; sq[tid] = 0.f; }

    const char* src = (const char*)(ybt + (((long)n*VJ + v)*TF)*CH);
    for (int qq = tid; qq < TCROWS*8; qq += 256) {
        int row = qq >> 3;
        int cb  = (qq & 7) << 4;
        int tg = row - 4;
        uint4 val = make_uint4(0u,0u,0u,0u);
        if (tg >= 0 && tg < TF)
            val = *(const uint4*)(src + (long)tg*128 + cb);
        *(uint4*)(ys + row*128 + (cb ^ ((row & 7) << 4))) = val;
    }
    __syncthreads();

    int wt0 = wv * 75;            // wave's t-quarter
    const short* aw = (const short*)awT;

    f32x4 acc[4][5];
    #pragma unroll
    for (int mf = 0; mf < 4; ++mf)
        #pragma unroll
        for (int nf = 0; nf < 5; ++nf)
            acc[mf][nf] = (f32x4){0.f,0.f,0.f,0.f};

    for (int tap = 0; tap < KW; ++tap) {
        #pragma unroll
        for (int kc = 0; kc < 2; ++kc) {
            s16x8 af[4], bfr[5];
            #pragma unroll
            for (int mf = 0; mf < 4; ++mf)
                af[mf] = *(const s16x8*)(aw + ((tap*CH + mf*16 + l15)*CH + kc*32 + lhi*8));
            #pragma unroll
            for (int nf = 0; nf < 5; ++nf) {
                int rloc = wt0 + nf*16 + l15 + tap;   // max 312 < 316
                int cb = (kc*64 + lhi*16) ^ ((rloc & 7) << 4);
                bfr[nf] = *(const s16x8*)(ys + rloc*128 + cb);
            }
            #pragma unroll
            for (int mf = 0; mf < 4; ++mf)
                #pragma unroll
                for (int nf = 0; nf < 5; ++nf)
                    acc[mf][nf] = __builtin_amdgcn_mfma_f32_16x16x32_bf16(
                        af[mf], bfr[nf], acc[mf][nf], 0, 0, 0);
        }
    }

    #pragma unroll
    for (int mf = 0; mf < 4; ++mf) {
        #pragma unroll
        for (int r = 0; r < 4; ++r) {
            int o = mf*16 + lhi*4 + r;
            float bo = bt[o];
            float p = 0.f, q = 0.f;
            #pragma unroll
            for (int nf = 0; nf < 5; ++nf) {
                int tle = nf*16 + l15;
                if (tle < 75) {
                    float val = acc[mf][nf][r] + bo;
                    ycb[(((long)n*CH + o)*VJ + v)*TF + wt0 + tle] = f2bf(val);
                    p += val; q += val*val;
                }
            }
            p += __shfl_xor(p, 1, 64); q += __shfl_xor(q, 1, 64);
            p += __shfl_xor(p, 2, 64); q += __shfl_xor(q, 2, 64);
            p += __shfl_xor(p, 4, 64); q += __shfl_xor(q, 4, 64);
            p += __shfl_xor(p, 8, 64); q += __shfl_xor(q, 8, 64);
            if (l15 == 0) { atomicAdd(&ss[o], p); atomicAdd(&sq[o], q); }
        }
    }
    __syncthreads();
    if (tid < 64) { atomicAdd(&s1[tid], ss[tid]); atomicAdd(&s2[tid], sq[tid]); }
}

// ------- out = relu(bn2(yc)+x): block=(n,c), LDS v<->t transpose ------------
__global__ __launch_bounds__(256) void k_out(
    const float* __restrict__ x, const float* __restrict__ g2, const float* __restrict__ b2,
    const float* __restrict__ s1, const float* __restrict__ s2,
    const unsigned short* __restrict__ ycb, float* __restrict__ out)
{
    __shared__ float ls[VJ*305];
    const float invN = 1.0f / (float)PCCOUNT;
    int b = blockIdx.x;
    int n = b >> 6, c = b & 63;
    int tid = threadIdx.x;

    float m  = s1[c] * invN;
    float vr = s2[c] * invN - m*m;
    float rs = rsqrtf(vr + EPSB) * g2[c];
    float bc = b2[c];

    const uint2* yc = (const uint2*)(ycb + ((long)n*CH + c)*TVsz);
    for (int e = tid; e < TVsz/4; e += 256) {
        uint2 d = yc[e];
        int base = e*4;
        int v = base / TF, t = base % TF;
        float* lp = &ls[v*305 + t];
        lp[0] = (bf2f(d.x & 0xffffu) - m)*rs + bc;
        lp[1] = (bf2f(d.x >> 16)     - m)*rs + bc;
        lp[2] = (bf2f(d.y & 0xffffu) - m)*rs + bc;
        lp[3] = (bf2f(d.y >> 16)     - m)*rs + bc;
    }
    __syncthreads();

    long gbase = ((long)n*CH + c)*TVsz;
    for (int e = tid; e < TVsz/4; e += 256) {
        int tv = e*4;
        float4 xv = *(const float4*)(x + gbase + tv);
        float4 ov;
        { int v = (tv+0) % 25, t = (tv+0) / 25; ov.x = fmaxf(ls[v*305 + t] + xv.x, 0.f); }
        { int v = (tv+1) % 25, t = (tv+1) / 25; ov.y = fmaxf(ls[v*305 + t] + xv.y, 0.f); }
        { int v = (tv+2) % 25, t = (tv+2) / 25; ov.z = fmaxf(ls[v*305 + t] + xv.z, 0.f); }
        { int v = (tv+3) % 25, t = (tv+3) / 25; ov.w = fmaxf(ls[v*305 + t] + xv.w, 0.f); }
        *(float4*)(out + gbase + tv) = ov;
    }
}

extern "C" void kernel_launch(void* const* d_in, const int* in_sizes, int n_in,
                              void* d_out, int out_size, void* d_ws, size_t ws_size,
                              hipStream_t stream) {
    const float* x  = (const float*)d_in[0];
    const float* A  = (const float*)d_in[1];
    const float* PA = (const float*)d_in[2];
    const float* Wa = (const float*)d_in[3];
    const float* ba = (const float*)d_in[4];
    const float* Wb = (const float*)d_in[5];
    const float* bb = (const float*)d_in[6];
    const float* Wd = (const float*)d_in[7];
    const float* bd = (const float*)d_in[8];
    const float* g1 = (const float*)d_in[9];
    const float* b1 = (const float*)d_in[10];
    const float* Wt = (const float*)d_in[11];
    const float* bt = (const float*)d_in[12];
    const float* g2 = (const float*)d_in[13];
    const float* b2 = (const float*)d_in[14];

    float* ws    = (float*)d_ws;
    float* Mbuf  = ws;                                        // [0, 60000)
    float* stats = ws + 60000;                                // [60000, 60256)
    unsigned short* wdcat  = (unsigned short*)(ws + 60256);   // -> 66400
    unsigned short* wcat   = (unsigned short*)(ws + 66400);   // -> 69472
    float* biascat = ws + 69472;                              // -> 69568
    unsigned short* awT    = (unsigned short*)(ws + 69568);   // -> 88000
    unsigned short* xbt    = (unsigned short*)(ws + 88000);   // 15.36M sh -> 7768000
    unsigned short* ybuf   = (unsigned short*)(ws + 7768000); // 15.36M sh -> 15448000
    unsigned short* ycb    = (unsigned short*)(ws + 15448000);// 15.36M sh -> 23128000
    unsigned short* ybt = xbt;                                // overlay after k_attn

    hipMemsetAsync(Mbuf, 0, (60000 + 256)*sizeof(float), stream);
    k_prep<<<217, 256, 0, stream>>>(Wt, Wd, Wa, ba, Wb, bb, awT, wdcat, wcat, biascat);
    k_xt<<<NB*118, 256, 0, stream>>>(x, xbt);
    k_attn<<<NSUB*NB*ATCN, 256, 0, stream>>>(xbt, wcat, biascat, Mbuf);
    k_softmax<<<NSUB*NB, 32, 0, stream>>>(A, PA, Mbuf);
    k_yz<<<NB*75, 256, 0, stream>>>(x, Mbuf, wdcat, bd, ybuf, stats, stats + 64);
    k_bn1t<<<NB*118, 256, 0, stream>>>(x, g1, b1, stats, stats + 64, ybuf, ybt);
    k_tconv<<<NB*VJ, 256, 0, stream>>>(ybt, awT, bt, ycb, stats + 128, stats + 192);
    k_out<<<NB*CH, 256, 0, stream>>>(x, g2, b2, stats + 128, stats + 192, ycb, (float*)d_out);
}